// Round 1
// baseline (19408.379 us; speedup 1.0000x reference)
//
#include <hip/hip_runtime.h>
#include <hip/hip_bf16.h>
#include <math.h>

#define B_    4
#define LSEQ  512
#define DE    1024
#define NH    16
#define DA    64
#define DMLP  4096
#define NV    32000
#define TOK   (B_ * LSEQ)
#define EPSF  1e-5f

// -------------------- embedding: out[(b*L+l)*DE + d] = We[id][d] + Wp[l][d] --------------------
__global__ __launch_bounds__(256)
void embed_kernel(const int* __restrict__ ids, const float* __restrict__ We,
                  const float* __restrict__ Wp, float* __restrict__ out)
{
    int tk = blockIdx.x;              // 0..TOK-1
    int l  = tk & (LSEQ - 1);
    int idx = ids[tk];
    const float* we = We + (size_t)idx * DE;
    const float* wp = Wp + (size_t)l * DE;
    float* o = out + (size_t)tk * DE;
    int d = threadIdx.x * 4;
    float4 a = *(const float4*)(we + d);
    float4 b = *(const float4*)(wp + d);
    float4 r; r.x = a.x + b.x; r.y = a.y + b.y; r.z = a.z + b.z; r.w = a.w + b.w;
    *(float4*)(o + d) = r;
}

// -------------------- generic NT GEMM: C[m,n] = sum_k A[m,k]*W[n,k] + bias[n] (+resid)(+relu) ----
// A: (TOK, K) fp32 row-major, W: (N, K) fp32 row-major. 64x64 tile, BK=16, 4x4 per thread.
__global__ __launch_bounds__(256)
void gemm_kernel(const float* __restrict__ A, const float* __restrict__ W,
                 const float* __restrict__ bias, const float* __restrict__ resid,
                 float* __restrict__ C, int N, int K, int relu)
{
    __shared__ float As[16][64];
    __shared__ float Ws[16][64];
    const int tid  = threadIdx.x;
    const int bm   = blockIdx.y << 6;
    const int bn   = blockIdx.x << 6;
    const int tx   = tid & 15, ty = tid >> 4;
    const int lrow = tid >> 2;
    const int lcol = (tid & 3) << 2;
    const float* Ap = A + (size_t)(bm + lrow) * K + lcol;
    const float* Wp = W + (size_t)(bn + lrow) * K + lcol;
    float acc[4][4] = {};
    for (int k0 = 0; k0 < K; k0 += 16) {
        float4 av = *(const float4*)(Ap + k0);
        float4 wv = *(const float4*)(Wp + k0);
        As[lcol + 0][lrow] = av.x; As[lcol + 1][lrow] = av.y;
        As[lcol + 2][lrow] = av.z; As[lcol + 3][lrow] = av.w;
        Ws[lcol + 0][lrow] = wv.x; Ws[lcol + 1][lrow] = wv.y;
        Ws[lcol + 2][lrow] = wv.z; Ws[lcol + 3][lrow] = wv.w;
        __syncthreads();
        #pragma unroll
        for (int k = 0; k < 16; ++k) {
            float4 a4 = *(const float4*)&As[k][ty << 2];
            float4 w4 = *(const float4*)&Ws[k][tx << 2];
            float aa[4] = {a4.x, a4.y, a4.z, a4.w};
            float ww[4] = {w4.x, w4.y, w4.z, w4.w};
            #pragma unroll
            for (int i = 0; i < 4; ++i)
                #pragma unroll
                for (int j = 0; j < 4; ++j)
                    acc[i][j] += aa[i] * ww[j];
        }
        __syncthreads();
    }
    #pragma unroll
    for (int i = 0; i < 4; ++i) {
        int m = bm + (ty << 2) + i;
        #pragma unroll
        for (int j = 0; j < 4; ++j) {
            int n = bn + (tx << 2) + j;
            float v = acc[i][j] + (bias ? bias[n] : 0.0f);
            if (resid) v += resid[(size_t)m * N + n];
            if (relu)  v = fmaxf(v, 0.0f);
            C[(size_t)m * N + n] = v;
        }
    }
}

// -------------------- unembed GEMM: logits into d_out layout (b, v, l), fp32 --------------------
__global__ __launch_bounds__(256)
void unembed_kernel(const float* __restrict__ A, const float* __restrict__ W,
                    float* __restrict__ out)
{
    __shared__ float As[16][64];
    __shared__ float Ws[16][64];
    const int tid  = threadIdx.x;
    const int bm   = blockIdx.y << 6;
    const int bn   = blockIdx.x << 6;
    const int tx   = tid & 15, ty = tid >> 4;
    const int lrow = tid >> 2;
    const int lcol = (tid & 3) << 2;
    const float* Ap = A + (size_t)(bm + lrow) * DE + lcol;
    const float* Wp = W + (size_t)(bn + lrow) * DE + lcol;
    float acc[4][4] = {};
    for (int k0 = 0; k0 < DE; k0 += 16) {
        float4 av = *(const float4*)(Ap + k0);
        float4 wv = *(const float4*)(Wp + k0);
        As[lcol + 0][lrow] = av.x; As[lcol + 1][lrow] = av.y;
        As[lcol + 2][lrow] = av.z; As[lcol + 3][lrow] = av.w;
        Ws[lcol + 0][lrow] = wv.x; Ws[lcol + 1][lrow] = wv.y;
        Ws[lcol + 2][lrow] = wv.z; Ws[lcol + 3][lrow] = wv.w;
        __syncthreads();
        #pragma unroll
        for (int k = 0; k < 16; ++k) {
            float4 a4 = *(const float4*)&As[k][ty << 2];
            float4 w4 = *(const float4*)&Ws[k][tx << 2];
            float aa[4] = {a4.x, a4.y, a4.z, a4.w};
            float ww[4] = {w4.x, w4.y, w4.z, w4.w};
            #pragma unroll
            for (int i = 0; i < 4; ++i)
                #pragma unroll
                for (int j = 0; j < 4; ++j)
                    acc[i][j] += aa[i] * ww[j];
        }
        __syncthreads();
    }
    #pragma unroll
    for (int i = 0; i < 4; ++i) {
        int m  = bm + (ty << 2) + i;
        int b2 = m >> 9;                 // m = b*LSEQ + lx
        int lx = m & (LSEQ - 1);
        #pragma unroll
        for (int j = 0; j < 4; ++j) {
            int n = bn + (tx << 2) + j;
            out[((size_t)b2 * NV + n) * LSEQ + lx] = acc[i][j];
        }
    }
}

// -------------------- attention: one workgroup per (qx, h, b); softmax over 512 keys ------------
__global__ __launch_bounds__(256)
void attn_kernel(const float* __restrict__ Qb, const float* __restrict__ Kb,
                 const float* __restrict__ Vb, float* __restrict__ Ctx, int causal)
{
    __shared__ float sc[LSEQ];
    __shared__ float qv[DA];
    __shared__ float red[256];
    const int qx  = blockIdx.x;
    const int h   = blockIdx.y;
    const int b   = blockIdx.z;
    const int tid = threadIdx.x;
    const size_t base = (size_t)b * LSEQ * DE + (size_t)h * DA;

    if (tid < DA) qv[tid] = Qb[base + (size_t)qx * DE + tid];
    __syncthreads();

    for (int kz = tid; kz < LSEQ; kz += 256) {
        float s = 0.0f;
        const float* kr = Kb + base + (size_t)kz * DE;
        #pragma unroll
        for (int a = 0; a < DA; a += 4) {
            float4 kk = *(const float4*)(kr + a);
            float4 qq = *(const float4*)(qv + a);
            s += kk.x * qq.x + kk.y * qq.y + kk.z * qq.z + kk.w * qq.w;
        }
        s *= 0.125f;                           // 1/sqrt(DA)
        if (causal && kz > qx) s = -INFINITY;  // key kz may attend to query qx iff kz <= qx
        sc[kz] = s;
    }
    __syncthreads();

    // max over 512
    float mx = fmaxf(sc[tid], sc[tid + 256]);
    red[tid] = mx; __syncthreads();
    for (int st = 128; st > 0; st >>= 1) {
        if (tid < st) red[tid] = fmaxf(red[tid], red[tid + st]);
        __syncthreads();
    }
    mx = red[0];
    __syncthreads();

    // exp + sum
    float ps = 0.0f;
    for (int kz = tid; kz < LSEQ; kz += 256) {
        float e = __expf(sc[kz] - mx);
        sc[kz] = e;
        ps += e;
    }
    red[tid] = ps; __syncthreads();
    for (int st = 128; st > 0; st >>= 1) {
        if (tid < st) red[tid] += red[tid + st];
        __syncthreads();
    }
    const float inv = 1.0f / red[0];
    __syncthreads();

    // ctx[o] = (1/denom) * sum_kz e[kz] * V[kz, o]
    const int o = tid & 63, g = tid >> 6;
    float acc = 0.0f;
    const float* vb = Vb + base + o;
    for (int kz = g * 128; kz < g * 128 + 128; ++kz)
        acc += sc[kz] * vb[(size_t)kz * DE];
    red[tid] = acc; __syncthreads();
    if (tid < 64) {
        float r = red[tid] + red[tid + 64] + red[tid + 128] + red[tid + 192];
        Ctx[base + (size_t)qx * DE + tid] = r * inv;
    }
}

// -------------------- layernorm over DE (ddof=1), per token ------------------------------------
__global__ __launch_bounds__(256)
void ln_kernel(const float* __restrict__ in, float* __restrict__ out,
               const float* __restrict__ g, const float* __restrict__ bb)
{
    __shared__ float red[256];
    const int tk  = blockIdx.x;
    const int tid = threadIdx.x;
    const float* xr = in + (size_t)tk * DE;
    float* orow = out + (size_t)tk * DE;
    const int d = tid * 4;
    float4 v = *(const float4*)(xr + d);

    float s = v.x + v.y + v.z + v.w;
    red[tid] = s; __syncthreads();
    for (int st = 128; st > 0; st >>= 1) {
        if (tid < st) red[tid] += red[tid + st];
        __syncthreads();
    }
    const float mean = red[0] * (1.0f / DE);
    __syncthreads();

    float dx = v.x - mean, dy = v.y - mean, dz = v.z - mean, dw = v.w - mean;
    red[tid] = dx * dx + dy * dy + dz * dz + dw * dw;
    __syncthreads();
    for (int st = 128; st > 0; st >>= 1) {
        if (tid < st) red[tid] += red[tid + st];
        __syncthreads();
    }
    const float var  = red[0] * (1.0f / (DE - 1));   // torch unbiased (ddof=1)
    const float rstd = rsqrtf(var + EPSF);

    float4 gg = *(const float4*)(g + d);
    float4 bb4 = *(const float4*)(bb + d);
    float4 r;
    r.x = dx * rstd * gg.x + bb4.x;
    r.y = dy * rstd * gg.y + bb4.y;
    r.z = dz * rstd * gg.z + bb4.z;
    r.w = dw * rstd * gg.w + bb4.w;
    *(float4*)(orow + d) = r;
}

// -------------------- vocab softmax in place over v axis; out layout (b, v, l) ------------------
__global__ __launch_bounds__(256)
void vocab_softmax_kernel(float* __restrict__ out)
{
    __shared__ float pm[4][64];
    __shared__ float ps[4][64];
    __shared__ float fm[64];
    __shared__ float fs[64];
    const int tid = threadIdx.x;
    const int tx  = tid & 63;
    const int ty  = tid >> 6;
    const int lx  = blockIdx.x * 64 + tx;
    const size_t bbase = (size_t)blockIdx.y * NV * LSEQ + lx;

    float m = -1e30f, s = 0.0f;
    for (int v = ty; v < NV; v += 4) {
        float w = out[bbase + (size_t)v * LSEQ];
        if (w > m) { s = s * __expf(m - w) + 1.0f; m = w; }
        else       { s += __expf(w - m); }
    }
    pm[ty][tx] = m; ps[ty][tx] = s;
    __syncthreads();
    if (ty == 0) {
        float M = pm[0][tx];
        #pragma unroll
        for (int g2 = 1; g2 < 4; ++g2) M = fmaxf(M, pm[g2][tx]);
        float S = 0.0f;
        #pragma unroll
        for (int g2 = 0; g2 < 4; ++g2) S += ps[g2][tx] * __expf(pm[g2][tx] - M);
        fm[tx] = M; fs[tx] = 1.0f / S;
    }
    __syncthreads();
    const float M = fm[tx], R = fs[tx];
    for (int v = ty; v < NV; v += 4) {
        size_t off = bbase + (size_t)v * LSEQ;
        out[off] = __expf(out[off] - M) * R;
    }
}

// ================================================================================================
extern "C" void kernel_launch(void* const* d_in, const int* in_sizes, int n_in,
                              void* d_out, int out_size, void* d_ws, size_t ws_size,
                              hipStream_t stream)
{
    (void)in_sizes; (void)n_in; (void)out_size; (void)ws_size;
    const int*   x  = (const int*)d_in[0];
    const int*   z  = (const int*)d_in[1];
    const float* We = (const float*)d_in[2];
    const float* Wp = (const float*)d_in[3];
    const float* Wu = (const float*)d_in[4];
    // per-phase weight blocks: 0 Wq,1 bq,2 Wk,3 bk,4 Wv,5 bv,6 Wo,7 bo,8 W1,9 b1,10 W2,11 b2
    const float* encW[12]; for (int i = 0; i < 12; ++i) encW[i] = (const float*)d_in[5 + i];
    const float* encLN[4]; for (int i = 0; i < 4;  ++i) encLN[i] = (const float*)d_in[17 + i];
    const float* decW[12]; for (int i = 0; i < 12; ++i) decW[i] = (const float*)d_in[21 + i];
    const float* decLN[6]; for (int i = 0; i < 6;  ++i) decLN[i] = (const float*)d_in[33 + i];
    float* out = (float*)d_out;

    float* Z  = (float*)d_ws;                 // (TOK, DE) encoder activations
    float* X  = Z  + (size_t)TOK * DE;        // (TOK, DE) decoder activations
    float* T  = X  + (size_t)TOK * DE;        // (TOK, DE) temp (pre-LN)
    float* Q  = T  + (size_t)TOK * DE;        // (TOK, DE)
    float* Kb = Q  + (size_t)TOK * DE;        // (TOK, DE)
    float* V  = Kb + (size_t)TOK * DE;        // (TOK, DE)
    float* Cx = V  + (size_t)TOK * DE;        // (TOK, DE) attention context (head-concat)
    float* Hb = Cx + (size_t)TOK * DE;        // (TOK, DMLP)

    auto gemm = [&](const float* A, const float* W, const float* bias,
                    const float* resid, float* C, int N, int K, int relu) {
        gemm_kernel<<<dim3(N / 64, TOK / 64), 256, 0, stream>>>(A, W, bias, resid, C, N, K, relu);
    };
    auto lnorm = [&](const float* in, float* o, const float* g, const float* bb) {
        ln_kernel<<<TOK, 256, 0, stream>>>(in, o, g, bb);
    };
    auto attn = [&](const float* q, const float* k, const float* v, float* c, int causal) {
        attn_kernel<<<dim3(LSEQ, NH, B_), 256, 0, stream>>>(q, k, v, c, causal);
    };

    // ---------------- encoder ----------------
    embed_kernel<<<TOK, 256, 0, stream>>>(z, We, Wp, Z);
    for (int l = 0; l < 2; ++l) {
        size_t wo  = (size_t)l * DE * DE;
        size_t bo  = (size_t)l * DE;
        size_t w1o = (size_t)l * DMLP * DE;
        size_t b1o = (size_t)l * DMLP;
        gemm(Z, encW[0] + wo, encW[1] + bo, nullptr, Q,  DE, DE, 0);
        gemm(Z, encW[2] + wo, encW[3] + bo, nullptr, Kb, DE, DE, 0);
        gemm(Z, encW[4] + wo, encW[5] + bo, nullptr, V,  DE, DE, 0);
        attn(Q, Kb, V, Cx, 0);
        gemm(Cx, encW[6] + wo, encW[7] + bo, Z, T, DE, DE, 0);
        lnorm(T, Z, encLN[0] + bo, encLN[1] + bo);
        gemm(Z, encW[8] + w1o, encW[9] + b1o, nullptr, Hb, DMLP, DE, 1);
        gemm(Hb, encW[10] + w1o, encW[11] + bo, Z, T, DE, DMLP, 0);
        lnorm(T, Z, encLN[2] + bo, encLN[3] + bo);
    }

    // ---------------- decoder ----------------
    embed_kernel<<<TOK, 256, 0, stream>>>(x, We, Wp, X);
    for (int l = 0; l < 2; ++l) {
        size_t wo  = (size_t)l * DE * DE;
        size_t bo  = (size_t)l * DE;
        size_t w1o = (size_t)l * DMLP * DE;
        size_t b1o = (size_t)l * DMLP;
        // self-attention (causal), weights shared with cross-attention
        gemm(X, decW[0] + wo, decW[1] + bo, nullptr, Q,  DE, DE, 0);
        gemm(X, decW[2] + wo, decW[3] + bo, nullptr, Kb, DE, DE, 0);
        gemm(X, decW[4] + wo, decW[5] + bo, nullptr, V,  DE, DE, 0);
        attn(Q, Kb, V, Cx, 1);
        gemm(Cx, decW[6] + wo, decW[7] + bo, X, T, DE, DE, 0);
        lnorm(T, X, decLN[0] + bo, decLN[1] + bo);
        // cross-attention: q from X, k/v from encoder output Z
        gemm(X, decW[0] + wo, decW[1] + bo, nullptr, Q,  DE, DE, 0);
        gemm(Z, decW[2] + wo, decW[3] + bo, nullptr, Kb, DE, DE, 0);
        gemm(Z, decW[4] + wo, decW[5] + bo, nullptr, V,  DE, DE, 0);
        attn(Q, Kb, V, Cx, 0);
        gemm(Cx, decW[6] + wo, decW[7] + bo, X, T, DE, DE, 0);
        lnorm(T, X, decLN[2] + bo, decLN[3] + bo);
        // MLP
        gemm(X, decW[8] + w1o, decW[9] + b1o, nullptr, Hb, DMLP, DE, 1);
        gemm(Hb, decW[10] + w1o, decW[11] + bo, X, T, DE, DMLP, 0);
        lnorm(T, X, decLN[4] + bo, decLN[5] + bo);
    }

    // ---------------- unembed + vocab softmax ----------------
    unembed_kernel<<<dim3(NV / 64, TOK / 64), 256, 0, stream>>>(X, Wu, out);
    vocab_softmax_kernel<<<dim3(LSEQ / 64, B_), 256, 0, stream>>>(out);
}

// Round 2
// 7764.767 us; speedup vs baseline: 2.4995x; 2.4995x over previous
//
#include <hip/hip_runtime.h>
#include <hip/hip_bf16.h>
#include <math.h>

#define B_    4
#define LSEQ  512
#define DE    1024
#define NH    16
#define DA    64
#define DMLP  4096
#define NV    32000
#define TOK   (B_ * LSEQ)
#define EPSF  1e-5f

typedef __attribute__((ext_vector_type(8))) short bf16x8;
typedef __attribute__((ext_vector_type(4))) float f32x4;

static __device__ __forceinline__ void gl_lds16(const void* g, void* l) {
    __builtin_amdgcn_global_load_lds((const __attribute__((address_space(1))) void*)g,
                                     (__attribute__((address_space(3))) void*)l, 16, 0, 0);
}
static __device__ __forceinline__ float bf2f(unsigned short u) {
    return __uint_as_float(((unsigned)u) << 16);
}
static __device__ __forceinline__ unsigned short f2bf(float f) {
    union { __hip_bfloat16 h; unsigned short s; } u;
    u.h = __float2bfloat16(f);
    return u.s;
}

// -------------------- fp32 -> bf16 convert (grid covers n/1024 blocks, 4 elems/thread) ----------
__global__ __launch_bounds__(256)
void convert_kernel(const float* __restrict__ src, unsigned short* __restrict__ dst)
{
    int i = (blockIdx.x * 256 + threadIdx.x) * 4;
    float4 v = *(const float4*)(src + i);
    ushort4 r;
    r.x = f2bf(v.x); r.y = f2bf(v.y); r.z = f2bf(v.z); r.w = f2bf(v.w);
    *(ushort4*)(dst + i) = r;
}

// -------------------- pack q/k/v biases into one 3072-float buffer -----------------------------
__global__ __launch_bounds__(256)
void pack_qkv_bias(const float* __restrict__ bq, const float* __restrict__ bk,
                   const float* __restrict__ bv, float* __restrict__ pb)
{
    int t = blockIdx.x * 256 + threadIdx.x;       // 0..3071
    float v = (t < 1024) ? bq[t] : (t < 2048) ? bk[t - 1024] : bv[t - 2048];
    pb[t] = v;
}

// -------------------- embedding: fp32 + bf16 outputs -------------------------------------------
__global__ __launch_bounds__(256)
void embed_kernel(const int* __restrict__ ids, const float* __restrict__ We,
                  const float* __restrict__ Wp, float* __restrict__ outf,
                  unsigned short* __restrict__ outb)
{
    int tk = blockIdx.x;
    int l  = tk & (LSEQ - 1);
    int idx = ids[tk];
    int d = threadIdx.x * 4;
    float4 a = *(const float4*)(We + (size_t)idx * DE + d);
    float4 b = *(const float4*)(Wp + (size_t)l * DE + d);
    float4 r; r.x = a.x + b.x; r.y = a.y + b.y; r.z = a.z + b.z; r.w = a.w + b.w;
    *(float4*)(outf + (size_t)tk * DE + d) = r;
    ushort4 rb; rb.x = f2bf(r.x); rb.y = f2bf(r.y); rb.z = f2bf(r.z); rb.w = f2bf(r.w);
    *(ushort4*)(outb + (size_t)tk * DE + d) = rb;
}

// -------------------- MFMA bf16 NT GEMM: C[m,n] = sum_k A[m,k]*W[n,k] ---------------------------
// A (TOK,K) bf16 row-major, W (N,K) bf16 row-major. 128x128 tile, BK=32, 4 waves (2x2 of 64x64).
// Output: bf16 (Cb) or fp32 (Cf) with row stride ldC; optional fp32 bias[n], resid[m*ldC+n], relu.
__global__ __launch_bounds__(256)
void gemm_bf16(const unsigned short* __restrict__ A, const unsigned short* __restrict__ W,
               const float* __restrict__ bias, const float* __restrict__ resid,
               float* __restrict__ Cf, unsigned short* __restrict__ Cb,
               int ldC, int K, int relu)
{
    __shared__ unsigned short Als[128 * 32];
    __shared__ unsigned short Wls[128 * 32];
    const int tid  = threadIdx.x;
    const int bm   = blockIdx.x << 7;           // m-tiles fastest: consecutive blocks share W tile
    const int bn   = blockIdx.y << 7;
    const int lane = tid & 63, wv = tid >> 6;
    const int wm   = (wv & 1) << 6, wn = (wv >> 1) << 6;
    const int fr   = lane & 15;                 // row-in-16 for frags, col for C
    const int fk   = (lane >> 4) << 3;          // k-offset for frags
    const int cr   = (lane >> 4) << 2;          // row base for C

    const unsigned short* Ag = A + (size_t)(bm + (tid >> 2)) * K + ((tid & 3) << 3);
    const unsigned short* Wg = W + (size_t)(bn + (tid >> 2)) * K + ((tid & 3) << 3);
    unsigned short* Al0 = Als + (tid << 3);
    unsigned short* Wl0 = Wls + (tid << 3);

    f32x4 acc[4][4];
    #pragma unroll
    for (int i = 0; i < 4; ++i)
        #pragma unroll
        for (int j = 0; j < 4; ++j) acc[i][j] = (f32x4){0.f, 0.f, 0.f, 0.f};

    for (int k0 = 0; k0 < K; k0 += 32) {
        gl_lds16(Ag + k0,                 Al0);
        gl_lds16(Ag + (size_t)64 * K + k0, Al0 + 2048);
        gl_lds16(Wg + k0,                 Wl0);
        gl_lds16(Wg + (size_t)64 * K + k0, Wl0 + 2048);
        __syncthreads();
        bf16x8 af[4], wf[4];
        #pragma unroll
        for (int i = 0; i < 4; ++i) af[i] = *(const bf16x8*)&Als[(wm + i * 16 + fr) * 32 + fk];
        #pragma unroll
        for (int j = 0; j < 4; ++j) wf[j] = *(const bf16x8*)&Wls[(wn + j * 16 + fr) * 32 + fk];
        #pragma unroll
        for (int i = 0; i < 4; ++i)
            #pragma unroll
            for (int j = 0; j < 4; ++j)
                acc[i][j] = __builtin_amdgcn_mfma_f32_16x16x32_bf16(af[i], wf[j], acc[i][j], 0, 0, 0);
        __syncthreads();
    }

    #pragma unroll
    for (int i = 0; i < 4; ++i) {
        #pragma unroll
        for (int j = 0; j < 4; ++j) {
            const int n = bn + wn + j * 16 + fr;
            const float bs = bias ? bias[n] : 0.0f;
            #pragma unroll
            for (int r = 0; r < 4; ++r) {
                const int m = bm + wm + i * 16 + cr + r;
                float v = acc[i][j][r] + bs;
                if (resid) v += resid[(size_t)m * ldC + n];
                if (relu)  v = fmaxf(v, 0.0f);
                if (Cb) Cb[(size_t)m * ldC + n] = f2bf(v);
                else    Cf[(size_t)m * ldC + n] = v;
            }
        }
    }
}

// -------------------- unembed: M = vocab (Wu fp32, converted in-kernel), N = tokens (Xb bf16) ---
// out[(b*NV + v)*LSEQ + lx] = dot(Wu[v], X[b,lx])   (coalesced stores along lx)
__global__ __launch_bounds__(256)
void unembed_kernel(const float* __restrict__ Wu, const unsigned short* __restrict__ Xb,
                    float* __restrict__ out)
{
    __shared__ float          Als[128 * 32];   // Wu tile fp32 (16 KB)
    __shared__ unsigned short Bls[128 * 32];   // X tile bf16 (8 KB)
    const int tid  = threadIdx.x;
    const int bm   = blockIdx.y << 7;          // vocab tile
    const int bn   = blockIdx.x << 7;          // token tile (fastest -> Wu L2 reuse)
    const int lane = tid & 63, wv = tid >> 6;
    const int wm   = (wv & 1) << 6, wn = (wv >> 1) << 6;
    const int fr   = lane & 15;
    const int fk   = (lane >> 4) << 3;
    const int cr   = (lane >> 4) << 2;

    const float* Ag = Wu + (size_t)(bm + (tid >> 3)) * DE + ((tid & 7) << 2);
    const unsigned short* Bg = Xb + (size_t)(bn + (tid >> 2)) * DE + ((tid & 3) << 3);
    float* Al0 = Als + (tid << 2);
    unsigned short* Bl0 = Bls + (tid << 3);

    f32x4 acc[4][4];
    #pragma unroll
    for (int i = 0; i < 4; ++i)
        #pragma unroll
        for (int j = 0; j < 4; ++j) acc[i][j] = (f32x4){0.f, 0.f, 0.f, 0.f};

    for (int k0 = 0; k0 < DE; k0 += 32) {
        #pragma unroll
        for (int q = 0; q < 4; ++q)
            gl_lds16(Ag + (size_t)q * 32 * DE + k0, Al0 + q * 1024);
        gl_lds16(Bg + k0,                  Bl0);
        gl_lds16(Bg + (size_t)64 * DE + k0, Bl0 + 2048);
        __syncthreads();
        bf16x8 af[4], bf[4];
        #pragma unroll
        for (int i = 0; i < 4; ++i) {
            const float* ap = &Als[(wm + i * 16 + fr) * 32 + fk];
            f32x4 u0 = *(const f32x4*)ap;
            f32x4 u1 = *(const f32x4*)(ap + 4);
            bf16x8 t;
            t[0] = (short)f2bf(u0[0]); t[1] = (short)f2bf(u0[1]);
            t[2] = (short)f2bf(u0[2]); t[3] = (short)f2bf(u0[3]);
            t[4] = (short)f2bf(u1[0]); t[5] = (short)f2bf(u1[1]);
            t[6] = (short)f2bf(u1[2]); t[7] = (short)f2bf(u1[3]);
            af[i] = t;
        }
        #pragma unroll
        for (int j = 0; j < 4; ++j) bf[j] = *(const bf16x8*)&Bls[(wn + j * 16 + fr) * 32 + fk];
        #pragma unroll
        for (int i = 0; i < 4; ++i)
            #pragma unroll
            for (int j = 0; j < 4; ++j)
                acc[i][j] = __builtin_amdgcn_mfma_f32_16x16x32_bf16(af[i], bf[j], acc[i][j], 0, 0, 0);
        __syncthreads();
    }

    #pragma unroll
    for (int i = 0; i < 4; ++i) {
        #pragma unroll
        for (int j = 0; j < 4; ++j) {
            const int tok = bn + wn + j * 16 + fr;
            const int b2  = tok >> 9;
            const int lx  = tok & (LSEQ - 1);
            #pragma unroll
            for (int r = 0; r < 4; ++r) {
                const int v = bm + wm + i * 16 + cr + r;
                out[((size_t)b2 * NV + v) * LSEQ + lx] = acc[i][j][r];
            }
        }
    }
}

// -------------------- attention on packed bf16 QKV (2048 x 3072: [q | k | v]) -------------------
__global__ __launch_bounds__(256)
void attn_kernel(const unsigned short* __restrict__ QKV, unsigned short* __restrict__ Ctx,
                 int causal)
{
    __shared__ float sc[LSEQ];
    __shared__ float qv[DA];
    __shared__ float red[256];
    const int qx  = blockIdx.x;
    const int h   = blockIdx.y;
    const int b   = blockIdx.z;
    const int tid = threadIdx.x;

    if (tid < DA) qv[tid] = bf2f(QKV[((size_t)(b * LSEQ + qx)) * 3072 + h * 64 + tid]);
    __syncthreads();

    for (int kz = tid; kz < LSEQ; kz += 256) {
        const uint4* kp = (const uint4*)(QKV + ((size_t)(b * LSEQ + kz)) * 3072 + 1024 + h * 64);
        float s = 0.0f;
        #pragma unroll
        for (int a2 = 0; a2 < 8; ++a2) {
            uint4 u = kp[a2];
            const int e = a2 * 8;
            s += __uint_as_float(u.x << 16) * qv[e + 0] + __uint_as_float(u.x & 0xffff0000u) * qv[e + 1];
            s += __uint_as_float(u.y << 16) * qv[e + 2] + __uint_as_float(u.y & 0xffff0000u) * qv[e + 3];
            s += __uint_as_float(u.z << 16) * qv[e + 4] + __uint_as_float(u.z & 0xffff0000u) * qv[e + 5];
            s += __uint_as_float(u.w << 16) * qv[e + 6] + __uint_as_float(u.w & 0xffff0000u) * qv[e + 7];
        }
        s *= 0.125f;
        if (causal && kz > qx) s = -INFINITY;
        sc[kz] = s;
    }
    __syncthreads();

    float mx = fmaxf(sc[tid], sc[tid + 256]);
    red[tid] = mx; __syncthreads();
    for (int st = 128; st > 0; st >>= 1) {
        if (tid < st) red[tid] = fmaxf(red[tid], red[tid + st]);
        __syncthreads();
    }
    mx = red[0];
    __syncthreads();

    float ps = 0.0f;
    for (int kz = tid; kz < LSEQ; kz += 256) {
        float e = __expf(sc[kz] - mx);
        sc[kz] = e;
        ps += e;
    }
    red[tid] = ps; __syncthreads();
    for (int st = 128; st > 0; st >>= 1) {
        if (tid < st) red[tid] += red[tid + st];
        __syncthreads();
    }
    const float inv = 1.0f / red[0];
    __syncthreads();

    const int o = tid & 63, g = tid >> 6;
    float acc = 0.0f;
    const unsigned short* vb = QKV + (size_t)b * LSEQ * 3072 + 2048 + h * 64 + o;
    for (int kz = g * 128; kz < g * 128 + 128; ++kz)
        acc += sc[kz] * bf2f(vb[(size_t)kz * 3072]);
    red[tid] = acc; __syncthreads();
    if (tid < 64) {
        float r = red[tid] + red[tid + 64] + red[tid + 128] + red[tid + 192];
        Ctx[((size_t)(b * LSEQ + qx)) * DE + h * 64 + tid] = f2bf(r * inv);
    }
}

// -------------------- layernorm over DE (ddof=1): fp32 in -> fp32 + bf16 out --------------------
__global__ __launch_bounds__(256)
void ln_kernel(const float* __restrict__ in, float* __restrict__ outf,
               unsigned short* __restrict__ outb,
               const float* __restrict__ g, const float* __restrict__ bb)
{
    __shared__ float red[256];
    const int tk  = blockIdx.x;
    const int tid = threadIdx.x;
    const float* xr = in + (size_t)tk * DE;
    const int d = tid * 4;
    float4 v = *(const float4*)(xr + d);

    red[tid] = v.x + v.y + v.z + v.w; __syncthreads();
    for (int st = 128; st > 0; st >>= 1) {
        if (tid < st) red[tid] += red[tid + st];
        __syncthreads();
    }
    const float mean = red[0] * (1.0f / DE);
    __syncthreads();

    float dx = v.x - mean, dy = v.y - mean, dz = v.z - mean, dw = v.w - mean;
    red[tid] = dx * dx + dy * dy + dz * dz + dw * dw;
    __syncthreads();
    for (int st = 128; st > 0; st >>= 1) {
        if (tid < st) red[tid] += red[tid + st];
        __syncthreads();
    }
    const float rstd = rsqrtf(red[0] * (1.0f / (DE - 1)) + EPSF);   // ddof=1

    float4 gg = *(const float4*)(g + d);
    float4 b4 = *(const float4*)(bb + d);
    float4 r;
    r.x = dx * rstd * gg.x + b4.x;
    r.y = dy * rstd * gg.y + b4.y;
    r.z = dz * rstd * gg.z + b4.z;
    r.w = dw * rstd * gg.w + b4.w;
    *(float4*)(outf + (size_t)tk * DE + d) = r;
    ushort4 rb; rb.x = f2bf(r.x); rb.y = f2bf(r.y); rb.z = f2bf(r.z); rb.w = f2bf(r.w);
    *(ushort4*)(outb + (size_t)tk * DE + d) = rb;
}

// -------------------- vocab softmax, 3-pass (out layout (b, v, l)) ------------------------------
#define VT1 50      // pass1 vocab tiles (640 v each)
__global__ __launch_bounds__(256)
void vsm_pass1(const float* __restrict__ out, float* __restrict__ Pm, float* __restrict__ Ps)
{
    __shared__ float sm[4][64], ss[4][64];
    const int tid = threadIdx.x, tx = tid & 63, ty = tid >> 6;
    const int l = blockIdx.x * 64 + tx, b = blockIdx.z, vt = blockIdx.y;
    const size_t base = ((size_t)b * NV + (size_t)vt * 640) * LSEQ + l;
    float m = -1e30f, s = 0.0f;
    for (int v = ty; v < 640; v += 4) {
        float w = out[base + (size_t)v * LSEQ];
        if (w > m) { s = s * __expf(m - w) + 1.0f; m = w; }
        else       { s += __expf(w - m); }
    }
    sm[ty][tx] = m; ss[ty][tx] = s;
    __syncthreads();
    if (ty == 0) {
        float M = sm[0][tx];
        #pragma unroll
        for (int q = 1; q < 4; ++q) M = fmaxf(M, sm[q][tx]);
        float S = 0.0f;
        #pragma unroll
        for (int q = 0; q < 4; ++q) S += ss[q][tx] * __expf(sm[q][tx] - M);
        const int tk = b * LSEQ + l;
        Pm[tk * VT1 + vt] = M;
        Ps[tk * VT1 + vt] = S;
    }
}

__global__ __launch_bounds__(256)
void vsm_pass2(const float* __restrict__ Pm, const float* __restrict__ Ps,
               float* __restrict__ Fm, float* __restrict__ Fr)
{
    const int tk = blockIdx.x * 256 + threadIdx.x;
    float M = -1e30f;
    for (int i = 0; i < VT1; ++i) M = fmaxf(M, Pm[tk * VT1 + i]);
    float S = 0.0f;
    for (int i = 0; i < VT1; ++i) S += Ps[tk * VT1 + i] * __expf(Pm[tk * VT1 + i] - M);
    Fm[tk] = M; Fr[tk] = 1.0f / S;
}

__global__ __launch_bounds__(256)
void vsm_pass3(float* __restrict__ out, const float* __restrict__ Fm, const float* __restrict__ Fr)
{
    const int tid = threadIdx.x, tx = tid & 63, ty = tid >> 6;
    const int l = blockIdx.x * 64 + tx, b = blockIdx.z;
    const int tk = b * LSEQ + l;
    const float M = Fm[tk], R = Fr[tk];
    const size_t base = ((size_t)b * NV + (size_t)blockIdx.y * 256) * LSEQ + l;
    for (int v = ty; v < 256; v += 4) {
        const size_t off = base + (size_t)v * LSEQ;
        out[off] = __expf(out[off] - M) * R;
    }
}

// ================================================================================================
extern "C" void kernel_launch(void* const* d_in, const int* in_sizes, int n_in,
                              void* d_out, int out_size, void* d_ws, size_t ws_size,
                              hipStream_t stream)
{
    (void)in_sizes; (void)n_in; (void)out_size; (void)ws_size;
    const int*   x  = (const int*)d_in[0];
    const int*   z  = (const int*)d_in[1];
    const float* We = (const float*)d_in[2];
    const float* Wp = (const float*)d_in[3];
    const float* Wu = (const float*)d_in[4];
    const float* encW[12]; for (int i = 0; i < 12; ++i) encW[i] = (const float*)d_in[5 + i];
    const float* encLN[4]; for (int i = 0; i < 4;  ++i) encLN[i] = (const float*)d_in[17 + i];
    const float* decW[12]; for (int i = 0; i < 12; ++i) decW[i] = (const float*)d_in[21 + i];
    const float* decLN[6]; for (int i = 0; i < 6;  ++i) decLN[i] = (const float*)d_in[33 + i];
    float* out = (float*)d_out;

    const size_t MB = 1024 * 1024;
    char* w = (char*)d_ws;
    float* Z            = (float*)(w + 0 * MB);          // 8 MB (reused for softmax partials)
    float* X            = (float*)(w + 8 * MB);          // 8 MB
    float* T            = (float*)(w + 16 * MB);         // 8 MB
    unsigned short* Zb  = (unsigned short*)(w + 24 * MB); // 4 MB
    unsigned short* Xb  = (unsigned short*)(w + 28 * MB); // 4 MB
    unsigned short* QKVb= (unsigned short*)(w + 32 * MB); // 12 MB (2048 x 3072)
    unsigned short* Cxb = (unsigned short*)(w + 44 * MB); // 4 MB
    unsigned short* Hb  = (unsigned short*)(w + 48 * MB); // 16 MB (2048 x 4096)
    unsigned short* Wqkvb = (unsigned short*)(w + 64 * MB); // 6 MB (3072 x 1024)
    unsigned short* Wob   = (unsigned short*)(w + 70 * MB); // 2 MB
    unsigned short* W1b   = (unsigned short*)(w + 72 * MB); // 8 MB
    unsigned short* W2b   = (unsigned short*)(w + 80 * MB); // 8 MB  -> 88 MB total
    float* pb = (float*)Hb;            // packed qkv bias; aliases Hb (dead until MLP1 writes it)
    float* Pm = Z;                     // softmax partials alias Z (dead after decoder loop)
    float* Ps = Z + (size_t)TOK * VT1;
    float* Fm = Z + (size_t)TOK * 2 * VT1;
    float* Fr = Fm + TOK;

    auto conv = [&](const float* s, unsigned short* d, int n) {
        convert_kernel<<<n / 1024, 256, 0, stream>>>(s, d);
    };
    auto gemm = [&](const unsigned short* A, const unsigned short* Wt, const float* bias,
                    const float* resid, float* Cf, unsigned short* Cb, int ldC, int ntiles,
                    int K, int relu) {
        gemm_bf16<<<dim3(TOK / 128, ntiles), 256, 0, stream>>>(A, Wt, bias, resid, Cf, Cb,
                                                               ldC, K, relu);
    };
    auto lnorm = [&](const float* in, float* of, unsigned short* ob,
                     const float* g, const float* bb) {
        ln_kernel<<<TOK, 256, 0, stream>>>(in, of, ob, g, bb);
    };
    auto attn = [&](unsigned short* ctx, int causal) {
        attn_kernel<<<dim3(LSEQ, NH, B_), 256, 0, stream>>>(QKVb, ctx, causal);
    };

    // ---------------- encoder ----------------
    embed_kernel<<<TOK, 256, 0, stream>>>(z, We, Wp, Z, Zb);
    for (int l = 0; l < 2; ++l) {
        const size_t wo  = (size_t)l * DE * DE;
        const size_t bo  = (size_t)l * DE;
        const size_t w1o = (size_t)l * DMLP * DE;
        const size_t b1o = (size_t)l * DMLP;
        conv(encW[0] + wo, Wqkvb,                 DE * DE);
        conv(encW[2] + wo, Wqkvb + DE * DE,       DE * DE);
        conv(encW[4] + wo, Wqkvb + 2 * DE * DE,   DE * DE);
        pack_qkv_bias<<<12, 256, 0, stream>>>(encW[1] + bo, encW[3] + bo, encW[5] + bo, pb);
        gemm(Zb, Wqkvb, pb, nullptr, nullptr, QKVb, 3072, 24, DE, 0);
        attn(Cxb, 0);
        conv(encW[6] + wo, Wob, DE * DE);
        gemm(Cxb, Wob, encW[7] + bo, Z, T, nullptr, DE, 8, DE, 0);
        lnorm(T, Z, Zb, encLN[0] + bo, encLN[1] + bo);
        conv(encW[8] + w1o, W1b, DMLP * DE);
        gemm(Zb, W1b, encW[9] + b1o, nullptr, nullptr, Hb, DMLP, 32, DE, 1);
        conv(encW[10] + w1o, W2b, DMLP * DE);
        gemm(Hb, W2b, encW[11] + bo, Z, T, nullptr, DE, 8, DMLP, 0);
        lnorm(T, Z, Zb, encLN[2] + bo, encLN[3] + bo);
    }

    // ---------------- decoder ----------------
    embed_kernel<<<TOK, 256, 0, stream>>>(x, We, Wp, X, Xb);
    for (int l = 0; l < 2; ++l) {
        const size_t wo  = (size_t)l * DE * DE;
        const size_t bo  = (size_t)l * DE;
        const size_t w1o = (size_t)l * DMLP * DE;
        const size_t b1o = (size_t)l * DMLP;
        conv(decW[0] + wo, Wqkvb,               DE * DE);
        conv(decW[2] + wo, Wqkvb + DE * DE,     DE * DE);
        conv(decW[4] + wo, Wqkvb + 2 * DE * DE, DE * DE);
        pack_qkv_bias<<<12, 256, 0, stream>>>(decW[1] + bo, decW[3] + bo, decW[5] + bo, pb);
        conv(decW[6] + wo, Wob, DE * DE);
        // self-attention (causal)
        gemm(Xb, Wqkvb, pb, nullptr, nullptr, QKVb, 3072, 24, DE, 0);
        attn(Cxb, 1);
        gemm(Cxb, Wob, decW[7] + bo, X, T, nullptr, DE, 8, DE, 0);
        lnorm(T, X, Xb, decLN[0] + bo, decLN[1] + bo);
        // cross-attention: Q from X, K/V from encoder Z (same weights)
        gemm(Xb, Wqkvb, pb, nullptr, nullptr, QKVb, 3072, 8, DE, 0);                     // Q
        gemm(Zb, Wqkvb + DE * DE, pb + 1024, nullptr, nullptr, QKVb + 1024, 3072, 16, DE, 0); // K,V
        attn(Cxb, 0);
        gemm(Cxb, Wob, decW[7] + bo, X, T, nullptr, DE, 8, DE, 0);
        lnorm(T, X, Xb, decLN[2] + bo, decLN[3] + bo);
        // MLP
        conv(decW[8] + w1o, W1b, DMLP * DE);
        gemm(Xb, W1b, decW[9] + b1o, nullptr, nullptr, Hb, DMLP, 32, DE, 1);
        conv(decW[10] + w1o, W2b, DMLP * DE);
        gemm(Hb, W2b, decW[11] + bo, X, T, nullptr, DE, 8, DMLP, 0);
        lnorm(T, X, Xb, decLN[4] + bo, decLN[5] + bo);
    }

    // ---------------- unembed + vocab softmax ----------------
    unembed_kernel<<<dim3(TOK / 128, NV / 128), 256, 0, stream>>>(Wu, Xb, out);
    vsm_pass1<<<dim3(LSEQ / 64, VT1, B_), 256, 0, stream>>>(out, Pm, Ps);
    vsm_pass2<<<TOK / 256, 256, 0, stream>>>(Pm, Ps, Fm, Fr);
    vsm_pass3<<<dim3(LSEQ / 64, NV / 256, B_), 256, 0, stream>>>(out, Fm, Fr);
}